// Round 8
// baseline (528.314 us; speedup 1.0000x reference)
//
#include <hip/hip_runtime.h>

#define TWO_PI_F 6.283185307179586f
#define LSTRIDE 258   // padded pairs per layer: slot 0 = identity (p=-1),
                      // slots 1..256 = pairs 0..255, slot 257 = identity (p=256)

__device__ __forceinline__ float clamp02pi(float x) {
    return fminf(fmaxf(x, 0.0f), TWO_PI_F);
}

// ---------------------------------------------------------------------------
// Kernel 1: coefficient precompute into PADDED arrays.
// cEp[k*258 + 1 + p] = (cos, sin, t, r) for even layer k, pair (2p, 2p+1).
// cOp[k*258 + 1 + p] = same for odd layer k, pair (2p+1, 2p+2).
// Identity at slots 0 and 257 (and cOp slot 256, p=255) so the mesh kernel's
// halo pairs need no branches and provably don't mix (r = 0).
// ---------------------------------------------------------------------------
__global__ __launch_bounds__(256) void coef_kernel(
    const float* __restrict__ pe, const float* __restrict__ po,
    const float* __restrict__ le, const float* __restrict__ ie,
    const float* __restrict__ lo, const float* __restrict__ io,
    float4* __restrict__ cEp, float4* __restrict__ cOp)
{
    const int k = blockIdx.x;    // layer 0..511
    const int p = threadIdx.x;   // pair  0..255
    {
        const int idx = k * 256 + p;
        float s, c;
        sincosf(clamp02pi(pe[idx]), &s, &c);
        const float a = sqrtf(1.0f - le[idx]);
        cEp[k * LSTRIDE + 1 + p] = make_float4(c, s, a * sqrtf(0.5f + ie[idx]),
                                                     a * sqrtf(0.5f - ie[idx]));
    }
    float4 q = make_float4(1.0f, 0.0f, 1.0f, 0.0f);
    if (p < 255) {
        const int idx = k * 255 + p;
        float s, c;
        sincosf(clamp02pi(po[idx]), &s, &c);
        const float a = sqrtf(1.0f - lo[idx]);
        q = make_float4(c, s, a * sqrtf(0.5f + io[idx]), a * sqrtf(0.5f - io[idx]));
    }
    cOp[k * LSTRIDE + 1 + p] = q;   // p == 255 -> identity
    if (p == 0) {
        const float4 id = make_float4(1.0f, 0.0f, 1.0f, 0.0f);
        cEp[k * LSTRIDE]       = id;  cOp[k * LSTRIDE]       = id;
        cEp[k * LSTRIDE + 257] = id;  cOp[k * LSTRIDE + 257] = id;
    }
}

// couple (top, bot) with q = (c, s, t, r): top gets phase e^{i th}, then
//   top' = t*pt + i*r*bot ; bot' = i*r*pt + t*bot.   (verified R5-R7)
__device__ __forceinline__ void couple(const float4 q, float2& top, float2& bot)
{
    const float pr = q.x * top.x - q.y * top.y;
    const float pi = q.x * top.y + q.y * top.x;
    const float ntx = q.z * pr - q.w * bot.y;
    const float nty = q.z * pi + q.w * bot.x;
    const float nbx = q.z * bot.x - q.w * pi;
    const float nby = q.z * bot.y + q.w * pr;
    top = make_float2(ntx, nty);
    bot = make_float2(nbx, nby);
}

struct Coefs { float4 e0[6], e1[6], o0[5], o1[5]; };

// Coefs for step i (layers k=2i, 2i+1). Lane base lb = 4*l: even pairs
// p = 4l-1+j (j=0..5) -> padded slot 4l+j; odd pairs p = 4l-1+j (j=0..4).
__device__ __forceinline__ void load_coefs(
    const float4* __restrict__ cEp, const float4* __restrict__ cOp,
    const int k, const int lb, Coefs& C)
{
    const float4* be0 = cEp + k * LSTRIDE + lb;
    const float4* be1 = be0 + LSTRIDE;
    const float4* bo0 = cOp + k * LSTRIDE + lb;
    const float4* bo1 = bo0 + LSTRIDE;
#pragma unroll
    for (int j = 0; j < 6; ++j) { C.e0[j] = be0[j]; C.e1[j] = be1[j]; }
#pragma unroll
    for (int j = 0; j < 5; ++j) { C.o0[j] = bo0[j]; C.o1[j] = bo1[j]; }
}

// One scan step (E0,E1,O0,O1) on the 12-row window R[0..11] = global rows
// 8l-2 .. 8l+9. Halo refresh = 8 INDEPENDENT shuffles (single latency window,
// hidden behind the 8 halo-free even couples). All couples lane-local.
__device__ __forceinline__ void step_body(float2 (&R)[12], const Coefs& C)
{
    // halo refresh: R[0],R[1] <- lane l-1's R[8],R[9]; R[10],R[11] <- lane
    // l+1's R[2],R[3]. Shuffles read pre-step values (sources not yet written).
    float2 h0, h1, h2, h3;
    h0.x = __shfl_up(R[8].x, 1);   h0.y = __shfl_up(R[8].y, 1);
    h1.x = __shfl_up(R[9].x, 1);   h1.y = __shfl_up(R[9].y, 1);
    h2.x = __shfl_down(R[2].x, 1); h2.y = __shfl_down(R[2].y, 1);
    h3.x = __shfl_down(R[3].x, 1); h3.y = __shfl_down(R[3].y, 1);

    // E0,E1 interior pairs (j=1..4): no halo dependency — covers shfl latency.
#pragma unroll
    for (int j = 1; j < 5; ++j) couple(C.e0[j], R[2 * j], R[2 * j + 1]);
#pragma unroll
    for (int j = 1; j < 5; ++j) couple(C.e1[j], R[2 * j], R[2 * j + 1]);

    // halo lands; E0,E1 on the two halo pairs.
    R[0] = h0; R[1] = h1; R[10] = h2; R[11] = h3;
    couple(C.e0[0], R[0], R[1]);   couple(C.e0[5], R[10], R[11]);
    couple(C.e1[0], R[0], R[1]);   couple(C.e1[5], R[10], R[11]);

    // O0,O1: pairs (R[1],R[2]),(R[3],R[4]),(R[5],R[6]),(R[7],R[8]),(R[9],R[10])
#pragma unroll
    for (int j = 0; j < 5; ++j) couple(C.o0[j], R[2 * j + 1], R[2 * j + 2]);
#pragma unroll
    for (int j = 0; j < 5; ++j) couple(C.o1[j], R[2 * j + 1], R[2 * j + 2]);
}

// ---------------------------------------------------------------------------
// Kernel 2: wave-per-column scan, zero barriers, one shuffle window per step.
// Grid 512 x 64. Lane l: canonical rows [8l, 8l+8) = R[2..9]; halo rows
// 8l-2,8l-1 (R[0,1]) and 8l+8,8l+9 (R[10,11]) recomputed redundantly
// (bitwise-identical to the owning lane's values). Edge lanes: out-of-range
// pairs use padded identity coefs; shuffled-in garbage is always finite and
// multiplied by exactly r=0 -> never contaminates kept rows.
// Coefs double-buffered via unroll-by-2 ping-pong (no rotation movs).
// ---------------------------------------------------------------------------
__global__ __launch_bounds__(64, 1) void mesh_halo_kernel(
    const float4* __restrict__ cEp, const float4* __restrict__ cOp,
    const float* __restrict__ pout,
    float* __restrict__ out, const int out_size)
{
    const int l   = threadIdx.x;   // lane 0..63
    const int col = blockIdx.x;    // column 0..511
    const int lb  = 4 * l;

    float2 R[12];
#pragma unroll
    for (int j = 0; j < 12; ++j)
        R[j] = make_float2((8 * l - 2 + j == col) ? 1.0f : 0.0f, 0.0f);
    // Init covers halo rows exactly, so step 0's shuffles (which read
    // neighbors' identical init values) are already consistent.

    Coefs A, B;
    load_coefs(cEp, cOp, 0, lb, A);

#pragma unroll 1
    for (int i = 0; i < 256; i += 2) {
        load_coefs(cEp, cOp, 2 * (i + 1), lb, B);          // prefetch step i+1
        step_body(R, A);                                   // step i
        load_coefs(cEp, cOp, (i + 2 < 256) ? 2 * (i + 2) : 0, lb, A);
        step_body(R, B);                                   // step i+1
    }

    // ---- output phases; expected output = Re(M), row-major, guarded ----
#pragma unroll
    for (int j = 0; j < 8; ++j) {
        const int r = 8 * l + j;
        float s, c;
        __sincosf(clamp02pi(pout[r]), &s, &c);
        const int o = r * 512 + col;
        if (o < out_size) out[o] = c * R[2 + j].x - s * R[2 + j].y;
    }
}

// ---------------------------------------------------------------------------
// Fallback (verbatim R5 kernel, known-passing) — used only if ws too small.
// ---------------------------------------------------------------------------
__global__ __launch_bounds__(256) void mesh_kernel(
    const float* __restrict__ pe, const float* __restrict__ po,
    const float* __restrict__ pout,
    const float* __restrict__ le, const float* __restrict__ ie,
    const float* __restrict__ lo, const float* __restrict__ io,
    float* __restrict__ out, const int out_size)
{
    const int p = threadIdx.x;
    const int b = blockIdx.x;

    __shared__ float4 P[2][256];

    P[0][p] = (p == b) ? make_float4(1.0f, 0.0f, 0.0f, 0.0f)
                       : make_float4(0.0f, 0.0f, 0.0f, 0.0f);
    P[1][p] = (p == b) ? make_float4(0.0f, 0.0f, 1.0f, 0.0f)
                       : make_float4(0.0f, 0.0f, 0.0f, 0.0f);

#pragma unroll 1
    for (int i = 0; i < 256; ++i) {
        const int e0 = (2 * i) * 256 + p, e1 = e0 + 256;
        const float pe0 = pe[e0], le0 = le[e0], ie0 = ie[e0];
        const float pe1 = pe[e1], le1 = le[e1], ie1 = ie[e1];
        float po0 = 0.0f, lo0 = 0.0f, io0 = 0.0f;
        float po1 = 0.0f, lo1 = 0.0f, io1 = 0.0f;
        if (p < 255) {
            const int o0 = (2 * i) * 255 + p, o1 = o0 + 255;
            po0 = po[o0]; lo0 = lo[o0]; io0 = io[o0];
            po1 = po[o1]; lo1 = lo[o1]; io1 = io[o1];
        }

        float4 v0 = P[0][p];
        float4 v1 = P[1][p];
#pragma unroll
        for (int j = 0; j < 2; ++j) {
            float s, c;
            __sincosf(clamp02pi(j ? pe1 : pe0), &s, &c);
            const float a  = sqrtf(1.0f - (j ? le1 : le0));
            const float tt = a * sqrtf(0.5f + (j ? ie1 : ie0));
            const float rr = a * sqrtf(0.5f - (j ? ie1 : ie0));
            {
                const float ptr_ = c * v0.x - s * v0.y;
                const float pti_ = c * v0.y + s * v0.x;
                v0 = make_float4(tt * ptr_ - rr * v0.w, tt * pti_ + rr * v0.z,
                                 tt * v0.z - rr * pti_, tt * v0.w + rr * ptr_);
            }
            {
                const float ptr_ = c * v1.x - s * v1.y;
                const float pti_ = c * v1.y + s * v1.x;
                v1 = make_float4(tt * ptr_ - rr * v1.w, tt * pti_ + rr * v1.z,
                                 tt * v1.z - rr * pti_, tt * v1.w + rr * ptr_);
            }
        }
        P[0][p] = v0;
        P[1][p] = v1;
        __syncthreads();

        if (p < 255) {
            float2 top0 = make_float2(P[0][p].z, P[0][p].w);
            float2 bot0 = make_float2(P[0][p + 1].x, P[0][p + 1].y);
            float2 top1 = make_float2(P[1][p].z, P[1][p].w);
            float2 bot1 = make_float2(P[1][p + 1].x, P[1][p + 1].y);
#pragma unroll
            for (int j = 0; j < 2; ++j) {
                float s, c;
                __sincosf(clamp02pi(j ? po1 : po0), &s, &c);
                const float a  = sqrtf(1.0f - (j ? lo1 : lo0));
                const float tt = a * sqrtf(0.5f + (j ? io1 : io0));
                const float rr = a * sqrtf(0.5f - (j ? io1 : io0));
                {
                    const float ptr_ = c * top0.x - s * top0.y;
                    const float pti_ = c * top0.y + s * top0.x;
                    const float nbx = tt * bot0.x - rr * pti_;
                    const float nby = tt * bot0.y + rr * ptr_;
                    top0 = make_float2(tt * ptr_ - rr * bot0.y, tt * pti_ + rr * bot0.x);
                    bot0 = make_float2(nbx, nby);
                }
                {
                    const float ptr_ = c * top1.x - s * top1.y;
                    const float pti_ = c * top1.y + s * top1.x;
                    const float nbx = tt * bot1.x - rr * pti_;
                    const float nby = tt * bot1.y + rr * ptr_;
                    top1 = make_float2(tt * ptr_ - rr * bot1.y, tt * pti_ + rr * bot1.x);
                    bot1 = make_float2(nbx, nby);
                }
            }
            P[0][p].z = top0.x; P[0][p].w = top0.y;
            P[0][p + 1].x = bot0.x; P[0][p + 1].y = bot0.y;
            P[1][p].z = top1.x; P[1][p].w = top1.y;
            P[1][p + 1].x = bot1.x; P[1][p + 1].y = bot1.y;
        }
        __syncthreads();
    }

    const float4 v0 = P[0][p];
    const float4 v1 = P[1][p];
    float s0, c0, s1, c1;
    __sincosf(clamp02pi(pout[2 * p]),     &s0, &c0);
    __sincosf(clamp02pi(pout[2 * p + 1]), &s1, &c1);

    float4 w0, w1;
    w0.x = c0 * v0.x - s0 * v0.y;  w0.y = c0 * v0.y + s0 * v0.x;
    w0.z = c0 * v1.x - s0 * v1.y;  w0.w = c0 * v1.y + s0 * v1.x;
    w1.x = c1 * v0.z - s1 * v0.w;  w1.y = c1 * v0.w + s1 * v0.z;
    w1.z = c1 * v1.z - s1 * v1.w;  w1.w = c1 * v1.w + s1 * v1.z;

    const int i0 = (2 * p) * 512 + 2 * b;
    const int i1 = (2 * p + 1) * 512 + 2 * b;
    if (i0 + 1 < out_size) *(float2*)(out + i0) = make_float2(w0.x, w0.z);
    if (i1 + 1 < out_size) *(float2*)(out + i1) = make_float2(w1.x, w1.z);
}

extern "C" void kernel_launch(void* const* d_in, const int* in_sizes, int n_in,
                              void* d_out, int out_size, void* d_ws, size_t ws_size,
                              hipStream_t stream)
{
    const float* pe   = (const float*)d_in[0];  // pc_even_phases  [512][256]
    const float* po   = (const float*)d_in[1];  // pc_odd_phases   [512][255]
    const float* pout = (const float*)d_in[2];  // pc_out_phases   [512]
    const float* le   = (const float*)d_in[3];  // mmi_loss_even   [512][256]
    const float* ie   = (const float*)d_in[4];  // mmi_imb_even    [512][256]
    const float* lo   = (const float*)d_in[5];  // mmi_loss_odd    [512][255]
    const float* io   = (const float*)d_in[6];  // mmi_imb_odd     [512][255]

    const size_t need = (size_t)2 * 512 * LSTRIDE * sizeof(float4);  // ~4.03 MB
    if (ws_size >= need) {
        float4* cEp = (float4*)d_ws;
        float4* cOp = cEp + 512 * LSTRIDE;
        coef_kernel<<<512, 256, 0, stream>>>(pe, po, le, ie, lo, io, cEp, cOp);
        mesh_halo_kernel<<<512, 64, 0, stream>>>(cEp, cOp, pout,
                                                 (float*)d_out, out_size);
    } else {
        mesh_kernel<<<256, 256, 0, stream>>>(pe, po, pout, le, ie, lo, io,
                                             (float*)d_out, out_size);
    }
}

// Round 9
// 451.352 us; speedup vs baseline: 1.1705x; 1.1705x over previous
//
#include <hip/hip_runtime.h>

#define TWO_PI_F 6.283185307179586f

__device__ __forceinline__ float clamp02pi(float x) {
    return fminf(fmaxf(x, 0.0f), TWO_PI_F);
}

// ---------------------------------------------------------------------------
// Kernel 1: coefficient precompute (verbatim R6/R7 — verified).
// coefE[k*256+p] = (cos, sin, t, r) for even layer k, pair (2p, 2p+1).
// coefO[k*256+p] = same for odd layer k, pair (2p+1, 2p+2); p=255 = identity.
// ---------------------------------------------------------------------------
__global__ __launch_bounds__(256) void coef_kernel(
    const float* __restrict__ pe, const float* __restrict__ po,
    const float* __restrict__ le, const float* __restrict__ ie,
    const float* __restrict__ lo, const float* __restrict__ io,
    float4* __restrict__ coefE, float4* __restrict__ coefO)
{
    const int k = blockIdx.x;    // layer 0..511
    const int p = threadIdx.x;   // pair  0..255
    {
        const int idx = k * 256 + p;
        float s, c;
        sincosf(clamp02pi(pe[idx]), &s, &c);
        const float a = sqrtf(1.0f - le[idx]);
        coefE[k * 256 + p] = make_float4(c, s, a * sqrtf(0.5f + ie[idx]),
                                               a * sqrtf(0.5f - ie[idx]));
    }
    float4 q = make_float4(1.0f, 0.0f, 1.0f, 0.0f);
    if (p < 255) {
        const int idx = k * 255 + p;
        float s, c;
        sincosf(clamp02pi(po[idx]), &s, &c);
        const float a = sqrtf(1.0f - lo[idx]);
        q = make_float4(c, s, a * sqrtf(0.5f + io[idx]), a * sqrtf(0.5f - io[idx]));
    }
    coefO[k * 256 + p] = q;
}

// couple (top, bot) with q = (c, s, t, r): top gets phase e^{i th}, then
//   top' = t*pt + i*r*bot ; bot' = i*r*pt + t*bot.   (verified R5-R8)
__device__ __forceinline__ void couple(const float4 q, float2& top, float2& bot)
{
    const float pr = q.x * top.x - q.y * top.y;
    const float pi = q.x * top.y + q.y * top.x;
    const float ntx = q.z * pr - q.w * bot.y;
    const float nty = q.z * pi + q.w * bot.x;
    const float nbx = q.z * bot.x - q.w * pi;
    const float nby = q.z * bot.y + q.w * pr;
    top = make_float2(ntx, nty);
    bot = make_float2(nbx, nby);
}

// Macros (NOT functions) so coef buffers stay plain register arrays with
// compile-time indices — R8's struct-by-reference idiom made SROA fail and
// spilled everything to scratch (VGPR_Count 56, 2.2x slowdown).
#define LOADC(CE, CO, k) \
    { \
        const int _b = (k) * 256 + lb; \
        CE[0] = coefE[_b];           CE[1] = coefE[_b + 1]; \
        CE[2] = coefE[_b + 2];       CE[3] = coefE[_b + 3]; \
        CE[4] = coefE[_b + 256];     CE[5] = coefE[_b + 257]; \
        CE[6] = coefE[_b + 258];     CE[7] = coefE[_b + 259]; \
        CO[0] = coefO[_b];           CO[1] = coefO[_b + 1]; \
        CO[2] = coefO[_b + 2];       CO[3] = coefO[_b + 3]; \
        CO[4] = coefO[_b + 256];     CO[5] = coefO[_b + 257]; \
        CO[6] = coefO[_b + 258];     CO[7] = coefO[_b + 259]; \
    }

// One scan step (E0,E1,O0,O1). Two shuffle windows only:
//   window A (top): lazily refresh T[0] (row 8l) from lane l-1's recv
//                   (row 8(l-1)+8 = 8l, final after lane l-1's odd couples).
//   window B (post-even): fetch lane l+1's T[0] (row 8l+8, post-even) into
//                   nr; both odd layers couple (B[3], nr) locally.
// Lane 63: CO[3]/CO[7] = pair 255 = identity (r=0) -> its garbage nr never
// contaminates kept rows. Lane 0: T[0] = row 0, untouched by odd layers.
#define STEP_BODY(CE, CO) \
    { \
        float2 up; \
        up.x = __shfl_up(recv.x, 1); \
        up.y = __shfl_up(recv.y, 1); \
        if (l > 0) T[0] = up; \
        couple(CE[0], T[0], B[0]); couple(CE[1], T[1], B[1]); \
        couple(CE[2], T[2], B[2]); couple(CE[3], T[3], B[3]); \
        couple(CE[4], T[0], B[0]); couple(CE[5], T[1], B[1]); \
        couple(CE[6], T[2], B[2]); couple(CE[7], T[3], B[3]); \
        float2 nr; \
        nr.x = __shfl_down(T[0].x, 1); \
        nr.y = __shfl_down(T[0].y, 1); \
        couple(CO[0], B[0], T[1]); couple(CO[1], B[1], T[2]); \
        couple(CO[2], B[2], T[3]); couple(CO[3], B[3], nr); \
        couple(CO[4], B[0], T[1]); couple(CO[5], B[1], T[2]); \
        couple(CO[6], B[2], T[3]); couple(CO[7], B[3], nr); \
        recv = nr; \
    }

// ---------------------------------------------------------------------------
// Kernel 2: wave-per-column scan, zero barriers, 2 shuffle windows per step.
// Grid 512 x 64. Lane l owns rows [8l, 8l+8): T[j] = row 8l+2j,
// B[j] = row 8l+2j+1, plus recv = row 8l+8 (lane l+1's top row, carried
// locally across both odd layers; lane l+1 refreshes lazily next step).
// Coefs double-buffered via unroll-by-2 ping-pong (plain arrays, no movs).
// ---------------------------------------------------------------------------
__global__ __launch_bounds__(64) void mesh_wave2_kernel(
    const float4* __restrict__ coefE,
    const float4* __restrict__ coefO,
    const float* __restrict__ pout,
    float* __restrict__ out, const int out_size)
{
    const int l   = threadIdx.x;   // lane 0..63
    const int col = blockIdx.x;    // column 0..511
    const int lb  = 4 * l;

    float2 T[4], B[4];
#pragma unroll
    for (int j = 0; j < 4; ++j) {
        T[j] = make_float2((8 * l + 2 * j     == col) ? 1.0f : 0.0f, 0.0f);
        B[j] = make_float2((8 * l + 2 * j + 1 == col) ? 1.0f : 0.0f, 0.0f);
    }
    float2 recv = make_float2((8 * l + 8 == col) ? 1.0f : 0.0f, 0.0f);

    float4 cA_E[8], cA_O[8], cB_E[8], cB_O[8];
    LOADC(cA_E, cA_O, 0);

#pragma unroll 1
    for (int i = 0; i < 256; i += 2) {
        LOADC(cB_E, cB_O, 2 * (i + 1));                    // prefetch step i+1
        STEP_BODY(cA_E, cA_O);                             // step i
        LOADC(cA_E, cA_O, (i + 2 < 256) ? 2 * (i + 2) : 0);
        STEP_BODY(cB_E, cB_O);                             // step i+1
    }

    // Final lazy T[0] refresh (last step's odd updates to row 8l live in
    // lane l-1's recv).
    {
        float2 up;
        up.x = __shfl_up(recv.x, 1);
        up.y = __shfl_up(recv.y, 1);
        if (l > 0) T[0] = up;
    }

    // ---- output phases; expected output = Re(M), row-major, guarded ----
#pragma unroll
    for (int j = 0; j < 4; ++j) {
        const int r0 = 8 * l + 2 * j;
        float s0, c0, s1, c1;
        __sincosf(clamp02pi(pout[r0]),     &s0, &c0);
        __sincosf(clamp02pi(pout[r0 + 1]), &s1, &c1);
        const int i0 = r0 * 512 + col;
        const int i1 = i0 + 512;
        if (i0 < out_size) out[i0] = c0 * T[j].x - s0 * T[j].y;
        if (i1 < out_size) out[i1] = c1 * B[j].x - s1 * B[j].y;
    }
}

// ---------------------------------------------------------------------------
// Fallback (verbatim R5 kernel, known-passing) — used only if ws too small.
// ---------------------------------------------------------------------------
__global__ __launch_bounds__(256) void mesh_kernel(
    const float* __restrict__ pe, const float* __restrict__ po,
    const float* __restrict__ pout,
    const float* __restrict__ le, const float* __restrict__ ie,
    const float* __restrict__ lo, const float* __restrict__ io,
    float* __restrict__ out, const int out_size)
{
    const int p = threadIdx.x;
    const int b = blockIdx.x;

    __shared__ float4 P[2][256];

    P[0][p] = (p == b) ? make_float4(1.0f, 0.0f, 0.0f, 0.0f)
                       : make_float4(0.0f, 0.0f, 0.0f, 0.0f);
    P[1][p] = (p == b) ? make_float4(0.0f, 0.0f, 1.0f, 0.0f)
                       : make_float4(0.0f, 0.0f, 0.0f, 0.0f);

#pragma unroll 1
    for (int i = 0; i < 256; ++i) {
        const int e0 = (2 * i) * 256 + p, e1 = e0 + 256;
        const float pe0 = pe[e0], le0 = le[e0], ie0 = ie[e0];
        const float pe1 = pe[e1], le1 = le[e1], ie1 = ie[e1];
        float po0 = 0.0f, lo0 = 0.0f, io0 = 0.0f;
        float po1 = 0.0f, lo1 = 0.0f, io1 = 0.0f;
        if (p < 255) {
            const int o0 = (2 * i) * 255 + p, o1 = o0 + 255;
            po0 = po[o0]; lo0 = lo[o0]; io0 = io[o0];
            po1 = po[o1]; lo1 = lo[o1]; io1 = io[o1];
        }

        float4 v0 = P[0][p];
        float4 v1 = P[1][p];
#pragma unroll
        for (int j = 0; j < 2; ++j) {
            float s, c;
            __sincosf(clamp02pi(j ? pe1 : pe0), &s, &c);
            const float a  = sqrtf(1.0f - (j ? le1 : le0));
            const float tt = a * sqrtf(0.5f + (j ? ie1 : ie0));
            const float rr = a * sqrtf(0.5f - (j ? ie1 : ie0));
            {
                const float ptr_ = c * v0.x - s * v0.y;
                const float pti_ = c * v0.y + s * v0.x;
                v0 = make_float4(tt * ptr_ - rr * v0.w, tt * pti_ + rr * v0.z,
                                 tt * v0.z - rr * pti_, tt * v0.w + rr * ptr_);
            }
            {
                const float ptr_ = c * v1.x - s * v1.y;
                const float pti_ = c * v1.y + s * v1.x;
                v1 = make_float4(tt * ptr_ - rr * v1.w, tt * pti_ + rr * v1.z,
                                 tt * v1.z - rr * pti_, tt * v1.w + rr * ptr_);
            }
        }
        P[0][p] = v0;
        P[1][p] = v1;
        __syncthreads();

        if (p < 255) {
            float2 top0 = make_float2(P[0][p].z, P[0][p].w);
            float2 bot0 = make_float2(P[0][p + 1].x, P[0][p + 1].y);
            float2 top1 = make_float2(P[1][p].z, P[1][p].w);
            float2 bot1 = make_float2(P[1][p + 1].x, P[1][p + 1].y);
#pragma unroll
            for (int j = 0; j < 2; ++j) {
                float s, c;
                __sincosf(clamp02pi(j ? po1 : po0), &s, &c);
                const float a  = sqrtf(1.0f - (j ? lo1 : lo0));
                const float tt = a * sqrtf(0.5f + (j ? io1 : io0));
                const float rr = a * sqrtf(0.5f - (j ? io1 : io0));
                {
                    const float ptr_ = c * top0.x - s * top0.y;
                    const float pti_ = c * top0.y + s * top0.x;
                    const float nbx = tt * bot0.x - rr * pti_;
                    const float nby = tt * bot0.y + rr * ptr_;
                    top0 = make_float2(tt * ptr_ - rr * bot0.y, tt * pti_ + rr * bot0.x);
                    bot0 = make_float2(nbx, nby);
                }
                {
                    const float ptr_ = c * top1.x - s * top1.y;
                    const float pti_ = c * top1.y + s * top1.x;
                    const float nbx = tt * bot1.x - rr * pti_;
                    const float nby = tt * bot1.y + rr * ptr_;
                    top1 = make_float2(tt * ptr_ - rr * bot1.y, tt * pti_ + rr * bot1.x);
                    bot1 = make_float2(nbx, nby);
                }
            }
            P[0][p].z = top0.x; P[0][p].w = top0.y;
            P[0][p + 1].x = bot0.x; P[0][p + 1].y = bot0.y;
            P[1][p].z = top1.x; P[1][p].w = top1.y;
            P[1][p + 1].x = bot1.x; P[1][p + 1].y = bot1.y;
        }
        __syncthreads();
    }

    const float4 v0 = P[0][p];
    const float4 v1 = P[1][p];
    float s0, c0, s1, c1;
    __sincosf(clamp02pi(pout[2 * p]),     &s0, &c0);
    __sincosf(clamp02pi(pout[2 * p + 1]), &s1, &c1);

    float4 w0, w1;
    w0.x = c0 * v0.x - s0 * v0.y;  w0.y = c0 * v0.y + s0 * v0.x;
    w0.z = c0 * v1.x - s0 * v1.y;  w0.w = c0 * v1.y + s0 * v1.x;
    w1.x = c1 * v0.z - s1 * v0.w;  w1.y = c1 * v0.w + s1 * v0.z;
    w1.z = c1 * v1.z - s1 * v1.w;  w1.w = c1 * v1.w + s1 * v1.z;

    const int i0 = (2 * p) * 512 + 2 * b;
    const int i1 = (2 * p + 1) * 512 + 2 * b;
    if (i0 + 1 < out_size) *(float2*)(out + i0) = make_float2(w0.x, w0.z);
    if (i1 + 1 < out_size) *(float2*)(out + i1) = make_float2(w1.x, w1.z);
}

extern "C" void kernel_launch(void* const* d_in, const int* in_sizes, int n_in,
                              void* d_out, int out_size, void* d_ws, size_t ws_size,
                              hipStream_t stream)
{
    const float* pe   = (const float*)d_in[0];  // pc_even_phases  [512][256]
    const float* po   = (const float*)d_in[1];  // pc_odd_phases   [512][255]
    const float* pout = (const float*)d_in[2];  // pc_out_phases   [512]
    const float* le   = (const float*)d_in[3];  // mmi_loss_even   [512][256]
    const float* ie   = (const float*)d_in[4];  // mmi_imb_even    [512][256]
    const float* lo   = (const float*)d_in[5];  // mmi_loss_odd    [512][255]
    const float* io   = (const float*)d_in[6];  // mmi_imb_odd     [512][255]

    const size_t need = (size_t)2 * 512 * 256 * sizeof(float4);  // 4 MB
    if (ws_size >= need) {
        float4* coefE = (float4*)d_ws;
        float4* coefO = coefE + 512 * 256;
        coef_kernel<<<512, 256, 0, stream>>>(pe, po, le, ie, lo, io, coefE, coefO);
        mesh_wave2_kernel<<<512, 64, 0, stream>>>(coefE, coefO, pout,
                                                  (float*)d_out, out_size);
    } else {
        mesh_kernel<<<256, 256, 0, stream>>>(pe, po, pout, le, ie, lo, io,
                                             (float*)d_out, out_size);
    }
}

// Round 10
// 426.509 us; speedup vs baseline: 1.2387x; 1.0582x over previous
//
#include <hip/hip_runtime.h>

#define TWO_PI_F 6.283185307179586f

__device__ __forceinline__ float clamp02pi(float x) {
    return fminf(fmaxf(x, 0.0f), TWO_PI_F);
}

__device__ __forceinline__ float2 cmul(const float2 a, const float2 b) {
    return make_float2(a.x * b.x - a.y * b.y, a.x * b.y + a.y * b.x);
}
__device__ __forceinline__ float2 cadd(const float2 a, const float2 b) {
    return make_float2(a.x + b.x, a.y + b.y);
}
__device__ __forceinline__ float2 cscale(const float s, const float2 a) {
    return make_float2(s * a.x, s * a.y);
}
__device__ __forceinline__ float2 imul(const float r, const float2 e) {  // i*r*e
    return make_float2(-r * e.y, r * e.x);
}

// ---------------------------------------------------------------------------
// Kernel 1: fused coef + step-composition.
// Block i = scan step (layers 2i, 2i+1). 512 threads: first compute all
// layer coefs (c,s,t,r) for both sub-layers into LDS, then each thread
// composes ROW r of M_step = O1*O0*E1*E0 — a banded row of 4 complex coefs
// over input cols [2*po, 2*po+4), po = (r-1)>>1. Row 0: cols 0,1 at slots
// 2,3 (base = -2). Output layout: Mc[(i*512 + r)*2 + h] = float4 of 2
// complex coefs (slots 2h, 2h+1).
// Couple 2x2 (verified R5-R9): top row [t*e, i*r], bot row [i*r*e, t].
// Composition algebra hand-verified vs sequential couples (row 0/1, cols
// 0..3, e=1, t=r=sqrt(.5) case).
// ---------------------------------------------------------------------------
__global__ __launch_bounds__(512) void compose_kernel(
    const float* __restrict__ pe, const float* __restrict__ po,
    const float* __restrict__ le, const float* __restrict__ ie,
    const float* __restrict__ lo, const float* __restrict__ io,
    float4* __restrict__ Mc)
{
    const int i = blockIdx.x;    // step 0..255
    const int t = threadIdx.x;   // 0..511

    __shared__ float4 sE[2][256];   // [sub-layer][even pair]
    __shared__ float4 sO[2][256];   // [sub-layer][odd pair]; 255 = identity

    {
        const int sub = t >> 8, pp = t & 255;
        const int k = 2 * i + sub;
        const int idx = k * 256 + pp;
        float s, c;
        sincosf(clamp02pi(pe[idx]), &s, &c);
        const float a = sqrtf(1.0f - le[idx]);
        sE[sub][pp] = make_float4(c, s, a * sqrtf(0.5f + ie[idx]),
                                        a * sqrtf(0.5f - ie[idx]));
        float4 q = make_float4(1.0f, 0.0f, 1.0f, 0.0f);
        if (pp < 255) {
            const int odx = k * 255 + pp;
            float so, co;
            sincosf(clamp02pi(po[odx]), &so, &co);
            const float ao = sqrtf(1.0f - lo[odx]);
            q = make_float4(co, so, ao * sqrtf(0.5f + io[odx]),
                                    ao * sqrtf(0.5f - io[odx]));
        }
        sO[sub][pp] = q;
    }
    __syncthreads();

    const int r = t;
    float2 f0, f1, f2, f3;
    if (r == 0) {
        // Row 0 untouched by odd layers: row0 of E1*E0, cols (0,1) -> slots 2,3.
        const float4 q1 = sE[1][0], q0 = sE[0][0];
        const float2 e1 = make_float2(q1.x, q1.y);
        const float2 e0 = make_float2(q0.x, q0.y);
        const float2 v2 = cscale(q1.z, e1);            // tE1*eE1
        const float2 v3 = make_float2(0.0f, q1.w);     // i*rE1
        f2 = cadd(cmul(v2, cscale(q0.z, e0)), cmul(v3, imul(q0.w, e0)));
        f3 = cadd(cmul(v2, make_float2(0.0f, q0.w)), cscale(q0.z, v3));
        f0 = make_float2(0.0f, 0.0f);
        f1 = make_float2(0.0f, 0.0f);
    } else {
        const int pidx = (r - 1) >> 1;            // odd-pair index AND even pair p
        const int qidx = min(pidx + 1, 255);      // r=511: u2==0, value unused
        // w = row r of O1 (within odd pair pidx = rows 2p+1, 2p+2)
        const float4 qO1 = sO[1][pidx], qO0 = sO[0][pidx];
        const float2 eO1 = make_float2(qO1.x, qO1.y);
        const float2 eO0 = make_float2(qO0.x, qO0.y);
        float2 w1, w2;
        if (r & 1) { w1 = cscale(qO1.z, eO1); w2 = make_float2(0.0f, qO1.w); }
        else       { w1 = imul(qO1.w, eO1);   w2 = make_float2(qO1.z, 0.0f); }
        // u = w * O0 (same pair)
        const float2 u1 = cadd(cmul(w1, cscale(qO0.z, eO0)),
                               cmul(w2, imul(qO0.w, eO0)));
        const float2 u2 = cadd(cmul(w1, make_float2(0.0f, qO0.w)),
                               cscale(qO0.z, w2));
        // v = u * E1: u1 at row 2p+1 (bot of even pair p), u2 at row 2p+2
        // (top of even pair p+1)
        const float4 qE1p = sE[1][pidx], qE1q = sE[1][qidx];
        const float4 qE0p = sE[0][pidx], qE0q = sE[0][qidx];
        const float2 eE1p = make_float2(qE1p.x, qE1p.y);
        const float2 eE1q = make_float2(qE1q.x, qE1q.y);
        const float2 eE0p = make_float2(qE0p.x, qE0p.y);
        const float2 eE0q = make_float2(qE0q.x, qE0q.y);
        const float2 v0 = cmul(u1, imul(qE1p.w, eE1p));
        const float2 v1 = cscale(qE1p.z, u1);
        const float2 v2 = cmul(u2, cscale(qE1q.z, eE1q));
        const float2 v3 = cmul(u2, make_float2(0.0f, qE1q.w));
        // f = v * E0
        f0 = cadd(cmul(v0, cscale(qE0p.z, eE0p)), cmul(v1, imul(qE0p.w, eE0p)));
        f1 = cadd(cmul(v0, make_float2(0.0f, qE0p.w)), cscale(qE0p.z, v1));
        f2 = cadd(cmul(v2, cscale(qE0q.z, eE0q)), cmul(v3, imul(qE0q.w, eE0q)));
        f3 = cadd(cmul(v2, make_float2(0.0f, qE0q.w)), cscale(qE0q.z, v3));
    }
    const int ob = (i * 512 + r) * 2;
    Mc[ob]     = make_float4(f0.x, f0.y, f1.x, f1.y);
    Mc[ob + 1] = make_float4(f2.x, f2.y, f3.x, f3.y);
}

// Banded row apply: out = c0.xy*a + c0.zw*b + c1.xy*d + c1.zw*e (complex).
__device__ __forceinline__ float2 row4(const float4 c0, const float4 c1,
                                       const float2 a, const float2 b,
                                       const float2 d, const float2 e)
{
    float re = c0.x * a.x - c0.y * a.y;
    float im = c0.x * a.y + c0.y * a.x;
    re += c0.z * b.x - c0.w * b.y;  im += c0.z * b.y + c0.w * b.x;
    re += c1.x * d.x - c1.y * d.y;  im += c1.x * d.y + c1.y * d.x;
    re += c1.z * e.x - c1.w * e.y;  im += c1.z * e.y + c1.w * e.x;
    return make_float2(re, im);
}

// Plain-array macros (R8 lesson: struct/ref idioms break SROA -> scratch).
#define LOADM(MB, ii) { \
    const float4* _p = Mc + ((ii) * 512 + 8 * l) * 2; \
    MB[0]  = _p[0];  MB[1]  = _p[1];  MB[2]  = _p[2];  MB[3]  = _p[3];  \
    MB[4]  = _p[4];  MB[5]  = _p[5];  MB[6]  = _p[6];  MB[7]  = _p[7];  \
    MB[8]  = _p[8];  MB[9]  = _p[9];  MB[10] = _p[10]; MB[11] = _p[11]; \
    MB[12] = _p[12]; MB[13] = _p[13]; MB[14] = _p[14]; MB[15] = _p[15]; \
}

// One composed step: single independent shuffle window (halo refresh), then
// 8 banded row-MACs, all lane-local. X[k] = row 8l-2+k. Row j even uses
// X[j..j+3]; odd uses X[j+1..j+4]. Edge garbage (lane 0 h0/h1, lane 63
// h2/h3) is finite and multiplied by exactly-zero coefs (rows 0/511).
#define STEPM(m) { \
    float2 h0, h1, h2, h3; \
    h0.x = __shfl_up(X[8].x, 1);   h0.y = __shfl_up(X[8].y, 1); \
    h1.x = __shfl_up(X[9].x, 1);   h1.y = __shfl_up(X[9].y, 1); \
    h2.x = __shfl_down(X[2].x, 1); h2.y = __shfl_down(X[2].y, 1); \
    h3.x = __shfl_down(X[3].x, 1); h3.y = __shfl_down(X[3].y, 1); \
    X[0] = h0; X[1] = h1; X[10] = h2; X[11] = h3; \
    const float2 Y0 = row4(m[0],  m[1],  X[0], X[1], X[2],  X[3]); \
    const float2 Y1 = row4(m[2],  m[3],  X[2], X[3], X[4],  X[5]); \
    const float2 Y2 = row4(m[4],  m[5],  X[2], X[3], X[4],  X[5]); \
    const float2 Y3 = row4(m[6],  m[7],  X[4], X[5], X[6],  X[7]); \
    const float2 Y4 = row4(m[8],  m[9],  X[4], X[5], X[6],  X[7]); \
    const float2 Y5 = row4(m[10], m[11], X[6], X[7], X[8],  X[9]); \
    const float2 Y6 = row4(m[12], m[13], X[6], X[7], X[8],  X[9]); \
    const float2 Y7 = row4(m[14], m[15], X[8], X[9], X[10], X[11]); \
    X[2] = Y0; X[3] = Y1; X[4] = Y2; X[5] = Y3; \
    X[6] = Y4; X[7] = Y5; X[8] = Y6; X[9] = Y7; \
}

// ---------------------------------------------------------------------------
// Kernel 2: banded-step scan. Grid 512 x 64, one wave per column, zero
// barriers, one shuffle window + 16 contiguous float4 loads + 128 FMA per
// step. Coefs double-buffered (2 x 16 float4); __launch_bounds__(64, 1)
// grants the full VGPR budget (R9 lesson: without min-waves the compiler
// picks a tight budget and spills).
// ---------------------------------------------------------------------------
__global__ __launch_bounds__(64, 1) void mesh_band_kernel(
    const float4* __restrict__ Mc,
    const float* __restrict__ pout,
    float* __restrict__ out, const int out_size)
{
    const int l   = threadIdx.x;   // lane 0..63
    const int col = blockIdx.x;    // column 0..511

    float2 X[12];
#pragma unroll
    for (int j = 0; j < 12; ++j)
        X[j] = make_float2((8 * l - 2 + j == col) ? 1.0f : 0.0f, 0.0f);

    float4 mA[16], mB[16];
    LOADM(mA, 0);

#pragma unroll 1
    for (int i = 0; i < 256; i += 2) {
        LOADM(mB, i + 1);                      // prefetch step i+1
        STEPM(mA);                             // step i
        LOADM(mA, (i + 2 < 256) ? i + 2 : 0);  // prefetch step i+2
        STEPM(mB);                             // step i+1
    }

    // ---- output phases; expected output = Re(M), row-major, guarded ----
#pragma unroll
    for (int j = 0; j < 8; ++j) {
        const int r = 8 * l + j;
        float s, c;
        __sincosf(clamp02pi(pout[r]), &s, &c);
        const int o = r * 512 + col;
        if (o < out_size) out[o] = c * X[2 + j].x - s * X[2 + j].y;
    }
}

// ---------------------------------------------------------------------------
// Fallback (verbatim R5 kernel, known-passing) — used only if ws too small.
// ---------------------------------------------------------------------------
__global__ __launch_bounds__(256) void mesh_kernel(
    const float* __restrict__ pe, const float* __restrict__ po,
    const float* __restrict__ pout,
    const float* __restrict__ le, const float* __restrict__ ie,
    const float* __restrict__ lo, const float* __restrict__ io,
    float* __restrict__ out, const int out_size)
{
    const int p = threadIdx.x;
    const int b = blockIdx.x;

    __shared__ float4 P[2][256];

    P[0][p] = (p == b) ? make_float4(1.0f, 0.0f, 0.0f, 0.0f)
                       : make_float4(0.0f, 0.0f, 0.0f, 0.0f);
    P[1][p] = (p == b) ? make_float4(0.0f, 0.0f, 1.0f, 0.0f)
                       : make_float4(0.0f, 0.0f, 0.0f, 0.0f);

#pragma unroll 1
    for (int i = 0; i < 256; ++i) {
        const int e0 = (2 * i) * 256 + p, e1 = e0 + 256;
        const float pe0 = pe[e0], le0 = le[e0], ie0 = ie[e0];
        const float pe1 = pe[e1], le1 = le[e1], ie1 = ie[e1];
        float po0 = 0.0f, lo0 = 0.0f, io0 = 0.0f;
        float po1 = 0.0f, lo1 = 0.0f, io1 = 0.0f;
        if (p < 255) {
            const int o0 = (2 * i) * 255 + p, o1 = o0 + 255;
            po0 = po[o0]; lo0 = lo[o0]; io0 = io[o0];
            po1 = po[o1]; lo1 = lo[o1]; io1 = io[o1];
        }

        float4 v0 = P[0][p];
        float4 v1 = P[1][p];
#pragma unroll
        for (int j = 0; j < 2; ++j) {
            float s, c;
            __sincosf(clamp02pi(j ? pe1 : pe0), &s, &c);
            const float a  = sqrtf(1.0f - (j ? le1 : le0));
            const float tt = a * sqrtf(0.5f + (j ? ie1 : ie0));
            const float rr = a * sqrtf(0.5f - (j ? ie1 : ie0));
            {
                const float ptr_ = c * v0.x - s * v0.y;
                const float pti_ = c * v0.y + s * v0.x;
                v0 = make_float4(tt * ptr_ - rr * v0.w, tt * pti_ + rr * v0.z,
                                 tt * v0.z - rr * pti_, tt * v0.w + rr * ptr_);
            }
            {
                const float ptr_ = c * v1.x - s * v1.y;
                const float pti_ = c * v1.y + s * v1.x;
                v1 = make_float4(tt * ptr_ - rr * v1.w, tt * pti_ + rr * v1.z,
                                 tt * v1.z - rr * pti_, tt * v1.w + rr * ptr_);
            }
        }
        P[0][p] = v0;
        P[1][p] = v1;
        __syncthreads();

        if (p < 255) {
            float2 top0 = make_float2(P[0][p].z, P[0][p].w);
            float2 bot0 = make_float2(P[0][p + 1].x, P[0][p + 1].y);
            float2 top1 = make_float2(P[1][p].z, P[1][p].w);
            float2 bot1 = make_float2(P[1][p + 1].x, P[1][p + 1].y);
#pragma unroll
            for (int j = 0; j < 2; ++j) {
                float s, c;
                __sincosf(clamp02pi(j ? po1 : po0), &s, &c);
                const float a  = sqrtf(1.0f - (j ? lo1 : lo0));
                const float tt = a * sqrtf(0.5f + (j ? io1 : io0));
                const float rr = a * sqrtf(0.5f - (j ? io1 : io0));
                {
                    const float ptr_ = c * top0.x - s * top0.y;
                    const float pti_ = c * top0.y + s * top0.x;
                    const float nbx = tt * bot0.x - rr * pti_;
                    const float nby = tt * bot0.y + rr * ptr_;
                    top0 = make_float2(tt * ptr_ - rr * bot0.y, tt * pti_ + rr * bot0.x);
                    bot0 = make_float2(nbx, nby);
                }
                {
                    const float ptr_ = c * top1.x - s * top1.y;
                    const float pti_ = c * top1.y + s * top1.x;
                    const float nbx = tt * bot1.x - rr * pti_;
                    const float nby = tt * bot1.y + rr * ptr_;
                    top1 = make_float2(tt * ptr_ - rr * bot1.y, tt * pti_ + rr * bot1.x);
                    bot1 = make_float2(nbx, nby);
                }
            }
            P[0][p].z = top0.x; P[0][p].w = top0.y;
            P[0][p + 1].x = bot0.x; P[0][p + 1].y = bot0.y;
            P[1][p].z = top1.x; P[1][p].w = top1.y;
            P[1][p + 1].x = bot1.x; P[1][p + 1].y = bot1.y;
        }
        __syncthreads();
    }

    const float4 v0 = P[0][p];
    const float4 v1 = P[1][p];
    float s0, c0, s1, c1;
    __sincosf(clamp02pi(pout[2 * p]),     &s0, &c0);
    __sincosf(clamp02pi(pout[2 * p + 1]), &s1, &c1);

    float4 w0, w1;
    w0.x = c0 * v0.x - s0 * v0.y;  w0.y = c0 * v0.y + s0 * v0.x;
    w0.z = c0 * v1.x - s0 * v1.y;  w0.w = c0 * v1.y + s0 * v1.x;
    w1.x = c1 * v0.z - s1 * v0.w;  w1.y = c1 * v0.w + s1 * v0.z;
    w1.z = c1 * v1.z - s1 * v1.w;  w1.w = c1 * v1.w + s1 * v1.z;

    const int i0 = (2 * p) * 512 + 2 * b;
    const int i1 = (2 * p + 1) * 512 + 2 * b;
    if (i0 + 1 < out_size) *(float2*)(out + i0) = make_float2(w0.x, w0.z);
    if (i1 + 1 < out_size) *(float2*)(out + i1) = make_float2(w1.x, w1.z);
}

extern "C" void kernel_launch(void* const* d_in, const int* in_sizes, int n_in,
                              void* d_out, int out_size, void* d_ws, size_t ws_size,
                              hipStream_t stream)
{
    const float* pe   = (const float*)d_in[0];  // pc_even_phases  [512][256]
    const float* po   = (const float*)d_in[1];  // pc_odd_phases   [512][255]
    const float* pout = (const float*)d_in[2];  // pc_out_phases   [512]
    const float* le   = (const float*)d_in[3];  // mmi_loss_even   [512][256]
    const float* ie   = (const float*)d_in[4];  // mmi_imb_even    [512][256]
    const float* lo   = (const float*)d_in[5];  // mmi_loss_odd    [512][255]
    const float* io   = (const float*)d_in[6];  // mmi_imb_odd     [512][255]

    const size_t need = (size_t)256 * 512 * 2 * sizeof(float4);  // 4 MB
    if (ws_size >= need) {
        float4* Mc = (float4*)d_ws;
        compose_kernel<<<256, 512, 0, stream>>>(pe, po, le, ie, lo, io, Mc);
        mesh_band_kernel<<<512, 64, 0, stream>>>(Mc, pout, (float*)d_out, out_size);
    } else {
        mesh_kernel<<<256, 256, 0, stream>>>(pe, po, pout, le, ie, lo, io,
                                             (float*)d_out, out_size);
    }
}

// Round 11
// 322.737 us; speedup vs baseline: 1.6370x; 1.3215x over previous
//
#include <hip/hip_runtime.h>

#define TWO_PI_F 6.283185307179586f

__device__ __forceinline__ float clamp02pi(float x) {
    return fminf(fmaxf(x, 0.0f), TWO_PI_F);
}

__device__ __forceinline__ float2 cmul(const float2 a, const float2 b) {
    return make_float2(a.x * b.x - a.y * b.y, a.x * b.y + a.y * b.x);
}
__device__ __forceinline__ float2 cadd(const float2 a, const float2 b) {
    return make_float2(a.x + b.x, a.y + b.y);
}
__device__ __forceinline__ float2 cscale(const float s, const float2 a) {
    return make_float2(s * a.x, s * a.y);
}
__device__ __forceinline__ float2 imul(const float r, const float2 e) {  // i*r*e
    return make_float2(-r * e.y, r * e.x);
}

// ---------------------------------------------------------------------------
// Kernel 1: fused coef + step-composition (math verbatim R10 — verified,
// absmax 1.86e-9). Only the OUTPUT LAYOUT changed: transposed for the mesh
// kernel's LDS access pattern.
//   row r -> slot (r&7)*64 + (r>>3);  Mc[i*1024 + h*512 + slot], h in {0,1}
//   h=0 holds band coefs (f0,f1), h=1 holds (f2,f3).
// Lane l (owning rows 8l+j) then reads LDS at 16 B lane-stride (2-way bank
// aliasing = free) instead of 256 B stride (16-way conflict).
// ---------------------------------------------------------------------------
__global__ __launch_bounds__(512) void compose_kernel(
    const float* __restrict__ pe, const float* __restrict__ po,
    const float* __restrict__ le, const float* __restrict__ ie,
    const float* __restrict__ lo, const float* __restrict__ io,
    float4* __restrict__ Mc)
{
    const int i = blockIdx.x;    // step 0..255
    const int t = threadIdx.x;   // 0..511

    __shared__ float4 sE[2][256];   // [sub-layer][even pair]
    __shared__ float4 sO[2][256];   // [sub-layer][odd pair]; 255 = identity

    {
        const int sub = t >> 8, pp = t & 255;
        const int k = 2 * i + sub;
        const int idx = k * 256 + pp;
        float s, c;
        sincosf(clamp02pi(pe[idx]), &s, &c);
        const float a = sqrtf(1.0f - le[idx]);
        sE[sub][pp] = make_float4(c, s, a * sqrtf(0.5f + ie[idx]),
                                        a * sqrtf(0.5f - ie[idx]));
        float4 q = make_float4(1.0f, 0.0f, 1.0f, 0.0f);
        if (pp < 255) {
            const int odx = k * 255 + pp;
            float so, co;
            sincosf(clamp02pi(po[odx]), &so, &co);
            const float ao = sqrtf(1.0f - lo[odx]);
            q = make_float4(co, so, ao * sqrtf(0.5f + io[odx]),
                                    ao * sqrtf(0.5f - io[odx]));
        }
        sO[sub][pp] = q;
    }
    __syncthreads();

    const int r = t;
    float2 f0, f1, f2, f3;
    if (r == 0) {
        const float4 q1 = sE[1][0], q0 = sE[0][0];
        const float2 e1 = make_float2(q1.x, q1.y);
        const float2 e0 = make_float2(q0.x, q0.y);
        const float2 v2 = cscale(q1.z, e1);
        const float2 v3 = make_float2(0.0f, q1.w);
        f2 = cadd(cmul(v2, cscale(q0.z, e0)), cmul(v3, imul(q0.w, e0)));
        f3 = cadd(cmul(v2, make_float2(0.0f, q0.w)), cscale(q0.z, v3));
        f0 = make_float2(0.0f, 0.0f);
        f1 = make_float2(0.0f, 0.0f);
    } else {
        const int pidx = (r - 1) >> 1;
        const int qidx = min(pidx + 1, 255);      // r=511: u2==0, value unused
        const float4 qO1 = sO[1][pidx], qO0 = sO[0][pidx];
        const float2 eO1 = make_float2(qO1.x, qO1.y);
        const float2 eO0 = make_float2(qO0.x, qO0.y);
        float2 w1, w2;
        if (r & 1) { w1 = cscale(qO1.z, eO1); w2 = make_float2(0.0f, qO1.w); }
        else       { w1 = imul(qO1.w, eO1);   w2 = make_float2(qO1.z, 0.0f); }
        const float2 u1 = cadd(cmul(w1, cscale(qO0.z, eO0)),
                               cmul(w2, imul(qO0.w, eO0)));
        const float2 u2 = cadd(cmul(w1, make_float2(0.0f, qO0.w)),
                               cscale(qO0.z, w2));
        const float4 qE1p = sE[1][pidx], qE1q = sE[1][qidx];
        const float4 qE0p = sE[0][pidx], qE0q = sE[0][qidx];
        const float2 eE1p = make_float2(qE1p.x, qE1p.y);
        const float2 eE1q = make_float2(qE1q.x, qE1q.y);
        const float2 eE0p = make_float2(qE0p.x, qE0p.y);
        const float2 eE0q = make_float2(qE0q.x, qE0q.y);
        const float2 v0 = cmul(u1, imul(qE1p.w, eE1p));
        const float2 v1 = cscale(qE1p.z, u1);
        const float2 v2 = cmul(u2, cscale(qE1q.z, eE1q));
        const float2 v3 = cmul(u2, make_float2(0.0f, qE1q.w));
        f0 = cadd(cmul(v0, cscale(qE0p.z, eE0p)), cmul(v1, imul(qE0p.w, eE0p)));
        f1 = cadd(cmul(v0, make_float2(0.0f, qE0p.w)), cscale(qE0p.z, v1));
        f2 = cadd(cmul(v2, cscale(qE0q.z, eE0q)), cmul(v3, imul(qE0q.w, eE0q)));
        f3 = cadd(cmul(v2, make_float2(0.0f, qE0q.w)), cscale(qE0q.z, v3));
    }
    const int slot = (r & 7) * 64 + (r >> 3);   // transposed: [j][lane]
    Mc[i * 1024 + slot]       = make_float4(f0.x, f0.y, f1.x, f1.y);
    Mc[i * 1024 + 512 + slot] = make_float4(f2.x, f2.y, f3.x, f3.y);
}

// Banded row apply: out = c0.xy*a + c0.zw*b + c1.xy*d + c1.zw*e (complex).
__device__ __forceinline__ float2 row4(const float4 c0, const float4 c1,
                                       const float2 a, const float2 b,
                                       const float2 d, const float2 e)
{
    float re = c0.x * a.x - c0.y * a.y;
    float im = c0.x * a.y + c0.y * a.x;
    re += c0.z * b.x - c0.w * b.y;  im += c0.z * b.y + c0.w * b.x;
    re += c1.x * d.x - c1.y * d.y;  im += c1.x * d.y + c1.y * d.x;
    re += c1.z * e.x - c1.w * e.y;  im += c1.z * e.y + c1.w * e.x;
    return make_float2(re, im);
}

// ---------------------------------------------------------------------------
// Kernel 2: banded-step scan with LDS-staged shared coefs.
// Grid 128 x 256: block = 4 waves = 4 columns (wave w -> column 4*bid+w);
// lane l holds rows [8l, 8l+8) of its wave's column in X[2..9], halo X[0,1]
// (rows 8l-2,8l-1) and X[10,11] refreshed per step via one independent
// shuffle window (verified R10). Coefs for the step (1024 float4 = 16 KB)
// are staged cooperatively into double-buffered LDS — each thread stages 4
// float4 (16 VGPRs of prefetch, nothing for the allocator to spill; R8-R10
// lesson: big register coef buffers always got sunk to scratch).
// One barrier per step. LDS reads: lane stride 16 B = 2-way = conflict-free.
// ---------------------------------------------------------------------------
__global__ __launch_bounds__(256, 1) void mesh_lds_kernel(
    const float4* __restrict__ Mc,
    const float* __restrict__ pout,
    float* __restrict__ out, const int out_size)
{
    const int t = threadIdx.x;
    const int w = t >> 6, l = t & 63;
    const int col = blockIdx.x * 4 + w;

    __shared__ float4 sC[2][1024];   // [buf][h*512 + j*64 + lane]

    float2 X[12];
#pragma unroll
    for (int j = 0; j < 12; ++j)
        X[j] = make_float2((8 * l - 2 + j == col) ? 1.0f : 0.0f, 0.0f);

    // prestage step 0
    {
        const float4 g0 = Mc[t], g1 = Mc[t + 256],
                     g2 = Mc[t + 512], g3 = Mc[t + 768];
        sC[0][t] = g0; sC[0][t + 256] = g1;
        sC[0][t + 512] = g2; sC[0][t + 768] = g3;
    }
    __syncthreads();

#pragma unroll 1
    for (int i = 0; i < 256; ++i) {
        // ---- global loads for step i+1 (latency hidden by compute) ----
        const int nb = ((i + 1) & 255) * 1024 + t;
        const float4 g0 = Mc[nb],      g1 = Mc[nb + 256],
                     g2 = Mc[nb + 512], g3 = Mc[nb + 768];

        // ---- halo refresh: one independent shuffle window ----
        float2 h0, h1, h2, h3;
        h0.x = __shfl_up(X[8].x, 1);   h0.y = __shfl_up(X[8].y, 1);
        h1.x = __shfl_up(X[9].x, 1);   h1.y = __shfl_up(X[9].y, 1);
        h2.x = __shfl_down(X[2].x, 1); h2.y = __shfl_down(X[2].y, 1);
        h3.x = __shfl_down(X[3].x, 1); h3.y = __shfl_down(X[3].y, 1);
        X[0] = h0; X[1] = h1; X[10] = h2; X[11] = h3;
        // Edge garbage (lane 0: X[0,1]; lane 63: X[10,11]) is finite and
        // multiplied by exactly-zero band coefs (rows 0 / 511) — verified R10.

        // ---- 8 banded row-MACs from LDS ----
        const float4* cb = sC[i & 1];
        const float2 Y0 = row4(cb[l],       cb[512 + l],       X[0], X[1], X[2],  X[3]);
        const float2 Y1 = row4(cb[64 + l],  cb[576 + l],       X[2], X[3], X[4],  X[5]);
        const float2 Y2 = row4(cb[128 + l], cb[640 + l],       X[2], X[3], X[4],  X[5]);
        const float2 Y3 = row4(cb[192 + l], cb[704 + l],       X[4], X[5], X[6],  X[7]);
        const float2 Y4 = row4(cb[256 + l], cb[768 + l],       X[4], X[5], X[6],  X[7]);
        const float2 Y5 = row4(cb[320 + l], cb[832 + l],       X[6], X[7], X[8],  X[9]);
        const float2 Y6 = row4(cb[384 + l], cb[896 + l],       X[6], X[7], X[8],  X[9]);
        const float2 Y7 = row4(cb[448 + l], cb[960 + l],       X[8], X[9], X[10], X[11]);
        X[2] = Y0; X[3] = Y1; X[4] = Y2; X[5] = Y3;
        X[6] = Y4; X[7] = Y5; X[8] = Y6; X[9] = Y7;

        // ---- stage step i+1 into the other buffer; sync ----
        float4* nbuf = sC[(i + 1) & 1];
        nbuf[t] = g0; nbuf[t + 256] = g1;
        nbuf[t + 512] = g2; nbuf[t + 768] = g3;
        __syncthreads();
    }

    // ---- output phases; expected output = Re(M), row-major, guarded ----
#pragma unroll
    for (int j = 0; j < 8; ++j) {
        const int r = 8 * l + j;
        float s, c;
        __sincosf(clamp02pi(pout[r]), &s, &c);
        const int o = r * 512 + col;
        if (o < out_size) out[o] = c * X[2 + j].x - s * X[2 + j].y;
    }
}

// ---------------------------------------------------------------------------
// Fallback (verbatim R5 kernel, known-passing) — used only if ws too small.
// ---------------------------------------------------------------------------
__global__ __launch_bounds__(256) void mesh_kernel(
    const float* __restrict__ pe, const float* __restrict__ po,
    const float* __restrict__ pout,
    const float* __restrict__ le, const float* __restrict__ ie,
    const float* __restrict__ lo, const float* __restrict__ io,
    float* __restrict__ out, const int out_size)
{
    const int p = threadIdx.x;
    const int b = blockIdx.x;

    __shared__ float4 P[2][256];

    P[0][p] = (p == b) ? make_float4(1.0f, 0.0f, 0.0f, 0.0f)
                       : make_float4(0.0f, 0.0f, 0.0f, 0.0f);
    P[1][p] = (p == b) ? make_float4(0.0f, 0.0f, 1.0f, 0.0f)
                       : make_float4(0.0f, 0.0f, 0.0f, 0.0f);

#pragma unroll 1
    for (int i = 0; i < 256; ++i) {
        const int e0 = (2 * i) * 256 + p, e1 = e0 + 256;
        const float pe0 = pe[e0], le0 = le[e0], ie0 = ie[e0];
        const float pe1 = pe[e1], le1 = le[e1], ie1 = ie[e1];
        float po0 = 0.0f, lo0 = 0.0f, io0 = 0.0f;
        float po1 = 0.0f, lo1 = 0.0f, io1 = 0.0f;
        if (p < 255) {
            const int o0 = (2 * i) * 255 + p, o1 = o0 + 255;
            po0 = po[o0]; lo0 = lo[o0]; io0 = io[o0];
            po1 = po[o1]; lo1 = lo[o1]; io1 = io[o1];
        }

        float4 v0 = P[0][p];
        float4 v1 = P[1][p];
#pragma unroll
        for (int j = 0; j < 2; ++j) {
            float s, c;
            __sincosf(clamp02pi(j ? pe1 : pe0), &s, &c);
            const float a  = sqrtf(1.0f - (j ? le1 : le0));
            const float tt = a * sqrtf(0.5f + (j ? ie1 : ie0));
            const float rr = a * sqrtf(0.5f - (j ? ie1 : ie0));
            {
                const float ptr_ = c * v0.x - s * v0.y;
                const float pti_ = c * v0.y + s * v0.x;
                v0 = make_float4(tt * ptr_ - rr * v0.w, tt * pti_ + rr * v0.z,
                                 tt * v0.z - rr * pti_, tt * v0.w + rr * ptr_);
            }
            {
                const float ptr_ = c * v1.x - s * v1.y;
                const float pti_ = c * v1.y + s * v1.x;
                v1 = make_float4(tt * ptr_ - rr * v1.w, tt * pti_ + rr * v1.z,
                                 tt * v1.z - rr * pti_, tt * v1.w + rr * ptr_);
            }
        }
        P[0][p] = v0;
        P[1][p] = v1;
        __syncthreads();

        if (p < 255) {
            float2 top0 = make_float2(P[0][p].z, P[0][p].w);
            float2 bot0 = make_float2(P[0][p + 1].x, P[0][p + 1].y);
            float2 top1 = make_float2(P[1][p].z, P[1][p].w);
            float2 bot1 = make_float2(P[1][p + 1].x, P[1][p + 1].y);
#pragma unroll
            for (int j = 0; j < 2; ++j) {
                float s, c;
                __sincosf(clamp02pi(j ? po1 : po0), &s, &c);
                const float a  = sqrtf(1.0f - (j ? lo1 : lo0));
                const float tt = a * sqrtf(0.5f + (j ? io1 : io0));
                const float rr = a * sqrtf(0.5f - (j ? io1 : io0));
                {
                    const float ptr_ = c * top0.x - s * top0.y;
                    const float pti_ = c * top0.y + s * top0.x;
                    const float nbx = tt * bot0.x - rr * pti_;
                    const float nby = tt * bot0.y + rr * ptr_;
                    top0 = make_float2(tt * ptr_ - rr * bot0.y, tt * pti_ + rr * bot0.x);
                    bot0 = make_float2(nbx, nby);
                }
                {
                    const float ptr_ = c * top1.x - s * top1.y;
                    const float pti_ = c * top1.y + s * top1.x;
                    const float nbx = tt * bot1.x - rr * pti_;
                    const float nby = tt * bot1.y + rr * ptr_;
                    top1 = make_float2(tt * ptr_ - rr * bot1.y, tt * pti_ + rr * bot1.x);
                    bot1 = make_float2(nbx, nby);
                }
            }
            P[0][p].z = top0.x; P[0][p].w = top0.y;
            P[0][p + 1].x = bot0.x; P[0][p + 1].y = bot0.y;
            P[1][p].z = top1.x; P[1][p].w = top1.y;
            P[1][p + 1].x = bot1.x; P[1][p + 1].y = bot1.y;
        }
        __syncthreads();
    }

    const float4 v0 = P[0][p];
    const float4 v1 = P[1][p];
    float s0, c0, s1, c1;
    __sincosf(clamp02pi(pout[2 * p]),     &s0, &c0);
    __sincosf(clamp02pi(pout[2 * p + 1]), &s1, &c1);

    float4 w0, w1;
    w0.x = c0 * v0.x - s0 * v0.y;  w0.y = c0 * v0.y + s0 * v0.x;
    w0.z = c0 * v1.x - s0 * v1.y;  w0.w = c0 * v1.y + s0 * v1.x;
    w1.x = c1 * v0.z - s1 * v0.w;  w1.y = c1 * v0.w + s1 * v0.z;
    w1.z = c1 * v1.z - s1 * v1.w;  w1.w = c1 * v1.w + s1 * v1.z;

    const int i0 = (2 * p) * 512 + 2 * b;
    const int i1 = (2 * p + 1) * 512 + 2 * b;
    if (i0 + 1 < out_size) *(float2*)(out + i0) = make_float2(w0.x, w0.z);
    if (i1 + 1 < out_size) *(float2*)(out + i1) = make_float2(w1.x, w1.z);
}

extern "C" void kernel_launch(void* const* d_in, const int* in_sizes, int n_in,
                              void* d_out, int out_size, void* d_ws, size_t ws_size,
                              hipStream_t stream)
{
    const float* pe   = (const float*)d_in[0];  // pc_even_phases  [512][256]
    const float* po   = (const float*)d_in[1];  // pc_odd_phases   [512][255]
    const float* pout = (const float*)d_in[2];  // pc_out_phases   [512]
    const float* le   = (const float*)d_in[3];  // mmi_loss_even   [512][256]
    const float* ie   = (const float*)d_in[4];  // mmi_imb_even    [512][256]
    const float* lo   = (const float*)d_in[5];  // mmi_loss_odd    [512][255]
    const float* io   = (const float*)d_in[6];  // mmi_imb_odd     [512][255]

    const size_t need = (size_t)256 * 1024 * sizeof(float4);  // 4 MB
    if (ws_size >= need) {
        float4* Mc = (float4*)d_ws;
        compose_kernel<<<256, 512, 0, stream>>>(pe, po, le, ie, lo, io, Mc);
        mesh_lds_kernel<<<128, 256, 0, stream>>>(Mc, pout, (float*)d_out, out_size);
    } else {
        mesh_kernel<<<256, 256, 0, stream>>>(pe, po, pout, le, ie, lo, io,
                                             (float*)d_out, out_size);
    }
}

// Round 12
// 172.408 us; speedup vs baseline: 3.0643x; 1.8719x over previous
//
#include <hip/hip_runtime.h>

#define TWO_PI_F 6.283185307179586f

__device__ __forceinline__ float clamp02pi(float x) {
    return fminf(fmaxf(x, 0.0f), TWO_PI_F);
}

__device__ __forceinline__ float2 cmul(const float2 a, const float2 b) {
    return make_float2(a.x * b.x - a.y * b.y, a.x * b.y + a.y * b.x);
}
__device__ __forceinline__ float2 cadd(const float2 a, const float2 b) {
    return make_float2(a.x + b.x, a.y + b.y);
}
__device__ __forceinline__ float2 cscale(const float s, const float2 a) {
    return make_float2(s * a.x, s * a.y);
}
__device__ __forceinline__ float2 imul(const float r, const float2 e) {  // i*r*e
    return make_float2(-r * e.y, r * e.x);
}

// ---------------------------------------------------------------------------
// Kernel 1: fused coef + step-composition (math verbatim R10/R11 — verified,
// absmax 1.86e-9; trig switched to HW __sincosf: error ~5e-7/layer,
// random-walk accumulated ~2e-11 absolute on the 1.5e-6-magnitude outputs).
// Row r of M_step = O1*O0*E1*E0 is a band of 4 complex coefs:
//   even r: cols r-2..r+1   (h0 = cols r-2,r-1; h1 = cols r,r+1)
//   odd  r: cols r-1..r+2   (h0 = cols r-1,r;   h1 = cols r+1,r+2)
// Output layout for the pair-thread mesh (t = r>>1):
//   even r: Mc[i*1024 +       t] = h0,  Mc[i*1024 + 256 + t] = h1
//   odd  r: Mc[i*1024 + 512 + t] = h0,  Mc[i*1024 + 768 + t] = h1
// ---------------------------------------------------------------------------
__global__ __launch_bounds__(512) void compose_kernel(
    const float* __restrict__ pe, const float* __restrict__ po,
    const float* __restrict__ le, const float* __restrict__ ie,
    const float* __restrict__ lo, const float* __restrict__ io,
    float4* __restrict__ Mc)
{
    const int i = blockIdx.x;    // step 0..255
    const int t = threadIdx.x;   // 0..511

    __shared__ float4 sE[2][256];   // [sub-layer][even pair]
    __shared__ float4 sO[2][256];   // [sub-layer][odd pair]; 255 = identity

    {
        const int sub = t >> 8, pp = t & 255;
        const int k = 2 * i + sub;
        const int idx = k * 256 + pp;
        float s, c;
        __sincosf(clamp02pi(pe[idx]), &s, &c);
        const float a = sqrtf(1.0f - le[idx]);
        sE[sub][pp] = make_float4(c, s, a * sqrtf(0.5f + ie[idx]),
                                        a * sqrtf(0.5f - ie[idx]));
        float4 q = make_float4(1.0f, 0.0f, 1.0f, 0.0f);
        if (pp < 255) {
            const int odx = k * 255 + pp;
            float so, co;
            __sincosf(clamp02pi(po[odx]), &so, &co);
            const float ao = sqrtf(1.0f - lo[odx]);
            q = make_float4(co, so, ao * sqrtf(0.5f + io[odx]),
                                    ao * sqrtf(0.5f - io[odx]));
        }
        sO[sub][pp] = q;
    }
    __syncthreads();

    const int r = t;
    float2 f0, f1, f2, f3;
    if (r == 0) {
        const float4 q1 = sE[1][0], q0 = sE[0][0];
        const float2 e1 = make_float2(q1.x, q1.y);
        const float2 e0 = make_float2(q0.x, q0.y);
        const float2 v2 = cscale(q1.z, e1);
        const float2 v3 = make_float2(0.0f, q1.w);
        f2 = cadd(cmul(v2, cscale(q0.z, e0)), cmul(v3, imul(q0.w, e0)));
        f3 = cadd(cmul(v2, make_float2(0.0f, q0.w)), cscale(q0.z, v3));
        f0 = make_float2(0.0f, 0.0f);
        f1 = make_float2(0.0f, 0.0f);
    } else {
        const int pidx = (r - 1) >> 1;
        const int qidx = min(pidx + 1, 255);      // r=511: u2==0, value unused
        const float4 qO1 = sO[1][pidx], qO0 = sO[0][pidx];
        const float2 eO1 = make_float2(qO1.x, qO1.y);
        const float2 eO0 = make_float2(qO0.x, qO0.y);
        float2 w1, w2;
        if (r & 1) { w1 = cscale(qO1.z, eO1); w2 = make_float2(0.0f, qO1.w); }
        else       { w1 = imul(qO1.w, eO1);   w2 = make_float2(qO1.z, 0.0f); }
        const float2 u1 = cadd(cmul(w1, cscale(qO0.z, eO0)),
                               cmul(w2, imul(qO0.w, eO0)));
        const float2 u2 = cadd(cmul(w1, make_float2(0.0f, qO0.w)),
                               cscale(qO0.z, w2));
        const float4 qE1p = sE[1][pidx], qE1q = sE[1][qidx];
        const float4 qE0p = sE[0][pidx], qE0q = sE[0][qidx];
        const float2 eE1p = make_float2(qE1p.x, qE1p.y);
        const float2 eE1q = make_float2(qE1q.x, qE1q.y);
        const float2 eE0p = make_float2(qE0p.x, qE0p.y);
        const float2 eE0q = make_float2(qE0q.x, qE0q.y);
        const float2 v0 = cmul(u1, imul(qE1p.w, eE1p));
        const float2 v1 = cscale(qE1p.z, u1);
        const float2 v2 = cmul(u2, cscale(qE1q.z, eE1q));
        const float2 v3 = cmul(u2, make_float2(0.0f, qE1q.w));
        f0 = cadd(cmul(v0, cscale(qE0p.z, eE0p)), cmul(v1, imul(qE0p.w, eE0p)));
        f1 = cadd(cmul(v0, make_float2(0.0f, qE0p.w)), cscale(qE0p.z, v1));
        f2 = cadd(cmul(v2, cscale(qE0q.z, eE0q)), cmul(v3, imul(qE0q.w, eE0q)));
        f3 = cadd(cmul(v2, make_float2(0.0f, qE0q.w)), cscale(qE0q.z, v3));
    }
    const int tp = r >> 1;
    const int base = i * 1024 + ((r & 1) ? 512 : 0) + tp;
    Mc[base]       = make_float4(f0.x, f0.y, f1.x, f1.y);
    Mc[base + 256] = make_float4(f2.x, f2.y, f3.x, f3.y);
}

// Banded row apply: out = c0.xy*a + c0.zw*b + c1.xy*d + c1.zw*e (complex).
__device__ __forceinline__ float2 row4(const float4 c0, const float4 c1,
                                       const float2 a, const float2 b,
                                       const float2 d, const float2 e)
{
    float re = c0.x * a.x - c0.y * a.y;
    float im = c0.x * a.y + c0.y * a.x;
    re += c0.z * b.x - c0.w * b.y;  im += c0.z * b.y + c0.w * b.x;
    re += c1.x * d.x - c1.y * d.y;  im += c1.x * d.y + c1.y * d.x;
    re += c1.z * e.x - c1.w * e.y;  im += c1.z * e.y + c1.w * e.x;
    return make_float2(re, im);
}

// ---------------------------------------------------------------------------
// Kernel 2: pair-thread banded scan. Grid 512 blocks x 256 threads:
// block = ONE column (full 256-CU coverage, 2 blocks/CU, 8 waves/CU = 2/SIMD
// — 4x R11's live waves). Thread t owns rows (2t, 2t+1) in registers; the
// neighbor pairs needed by the band come from double-buffered LDS state
// (float4/thread, lane stride 16 B = 2-way = conflict-free), ONE barrier per
// step. Per-thread coefs: 4 float4 prefetched into named registers (R8-R10
// lesson: no register arrays -> nothing to sink to scratch; ~60 VGPRs).
//   row 2t   (even): row4(c0, c1, below.T, below.B, T, B)
//   row 2t+1 (odd) : row4(c2, c3, T, B, above.T, above.B)
// Edge clamps feed finite garbage into exactly-zero band coefs (rows 0/511
// have f0,f1 / f2,f3 = 0 by construction — verified R10/R11).
// ---------------------------------------------------------------------------
__global__ __launch_bounds__(256) void mesh_pair_kernel(
    const float4* __restrict__ Mc,
    const float* __restrict__ pout,
    float* __restrict__ out, const int out_size)
{
    const int t   = threadIdx.x;   // row-pair 0..255
    const int col = blockIdx.x;    // column 0..511

    __shared__ float4 S[2][256];   // [buf][pair] = {T.x, T.y, B.x, B.y}

    float2 T = make_float2((2 * t     == col) ? 1.0f : 0.0f, 0.0f);
    float2 B = make_float2((2 * t + 1 == col) ? 1.0f : 0.0f, 0.0f);
    S[0][t] = make_float4(T.x, T.y, B.x, B.y);

    const int tm = (t > 0) ? t - 1 : 0;
    const int tp = (t < 255) ? t + 1 : 255;

    // current-step coefs (named registers, not arrays)
    float4 c0 = Mc[t], c1 = Mc[256 + t], c2 = Mc[512 + t], c3 = Mc[768 + t];
    __syncthreads();

#pragma unroll 1
    for (int i = 0; i < 256; ++i) {
        // prefetch next step's coefs (wraps at 255; harmless)
        const int nb = ((i + 1) & 255) * 1024 + t;
        const float4 n0 = Mc[nb],       n1 = Mc[nb + 256],
                     n2 = Mc[nb + 512], n3 = Mc[nb + 768];

        const float4 below = S[i & 1][tm];
        const float4 above = S[i & 1][tp];

        const float2 Ye = row4(c0, c1, make_float2(below.x, below.y),
                                       make_float2(below.z, below.w), T, B);
        const float2 Yo = row4(c2, c3, T, B, make_float2(above.x, above.y),
                                             make_float2(above.z, above.w));
        T = Ye; B = Yo;
        S[(i + 1) & 1][t] = make_float4(T.x, T.y, B.x, B.y);
        __syncthreads();

        c0 = n0; c1 = n1; c2 = n2; c3 = n3;
    }

    // ---- output phases; expected output = Re(M), row-major, guarded ----
    float s0, cc0, s1, cc1;
    __sincosf(clamp02pi(pout[2 * t]),     &s0, &cc0);
    __sincosf(clamp02pi(pout[2 * t + 1]), &s1, &cc1);
    const int i0 = (2 * t) * 512 + col;
    const int i1 = i0 + 512;
    if (i0 < out_size) out[i0] = cc0 * T.x - s0 * T.y;
    if (i1 < out_size) out[i1] = cc1 * B.x - s1 * B.y;
}

// ---------------------------------------------------------------------------
// Fallback (verbatim R5 kernel, known-passing) — used only if ws too small.
// ---------------------------------------------------------------------------
__global__ __launch_bounds__(256) void mesh_kernel(
    const float* __restrict__ pe, const float* __restrict__ po,
    const float* __restrict__ pout,
    const float* __restrict__ le, const float* __restrict__ ie,
    const float* __restrict__ lo, const float* __restrict__ io,
    float* __restrict__ out, const int out_size)
{
    const int p = threadIdx.x;
    const int b = blockIdx.x;

    __shared__ float4 P[2][256];

    P[0][p] = (p == b) ? make_float4(1.0f, 0.0f, 0.0f, 0.0f)
                       : make_float4(0.0f, 0.0f, 0.0f, 0.0f);
    P[1][p] = (p == b) ? make_float4(0.0f, 0.0f, 1.0f, 0.0f)
                       : make_float4(0.0f, 0.0f, 0.0f, 0.0f);

#pragma unroll 1
    for (int i = 0; i < 256; ++i) {
        const int e0 = (2 * i) * 256 + p, e1 = e0 + 256;
        const float pe0 = pe[e0], le0 = le[e0], ie0 = ie[e0];
        const float pe1 = pe[e1], le1 = le[e1], ie1 = ie[e1];
        float po0 = 0.0f, lo0 = 0.0f, io0 = 0.0f;
        float po1 = 0.0f, lo1 = 0.0f, io1 = 0.0f;
        if (p < 255) {
            const int o0 = (2 * i) * 255 + p, o1 = o0 + 255;
            po0 = po[o0]; lo0 = lo[o0]; io0 = io[o0];
            po1 = po[o1]; lo1 = lo[o1]; io1 = io[o1];
        }

        float4 v0 = P[0][p];
        float4 v1 = P[1][p];
#pragma unroll
        for (int j = 0; j < 2; ++j) {
            float s, c;
            __sincosf(clamp02pi(j ? pe1 : pe0), &s, &c);
            const float a  = sqrtf(1.0f - (j ? le1 : le0));
            const float tt = a * sqrtf(0.5f + (j ? ie1 : ie0));
            const float rr = a * sqrtf(0.5f - (j ? ie1 : ie0));
            {
                const float ptr_ = c * v0.x - s * v0.y;
                const float pti_ = c * v0.y + s * v0.x;
                v0 = make_float4(tt * ptr_ - rr * v0.w, tt * pti_ + rr * v0.z,
                                 tt * v0.z - rr * pti_, tt * v0.w + rr * ptr_);
            }
            {
                const float ptr_ = c * v1.x - s * v1.y;
                const float pti_ = c * v1.y + s * v1.x;
                v1 = make_float4(tt * ptr_ - rr * v1.w, tt * pti_ + rr * v1.z,
                                 tt * v1.z - rr * pti_, tt * v1.w + rr * ptr_);
            }
        }
        P[0][p] = v0;
        P[1][p] = v1;
        __syncthreads();

        if (p < 255) {
            float2 top0 = make_float2(P[0][p].z, P[0][p].w);
            float2 bot0 = make_float2(P[0][p + 1].x, P[0][p + 1].y);
            float2 top1 = make_float2(P[1][p].z, P[1][p].w);
            float2 bot1 = make_float2(P[1][p + 1].x, P[1][p + 1].y);
#pragma unroll
            for (int j = 0; j < 2; ++j) {
                float s, c;
                __sincosf(clamp02pi(j ? po1 : po0), &s, &c);
                const float a  = sqrtf(1.0f - (j ? lo1 : lo0));
                const float tt = a * sqrtf(0.5f + (j ? io1 : io0));
                const float rr = a * sqrtf(0.5f - (j ? io1 : io0));
                {
                    const float ptr_ = c * top0.x - s * top0.y;
                    const float pti_ = c * top0.y + s * top0.x;
                    const float nbx = tt * bot0.x - rr * pti_;
                    const float nby = tt * bot0.y + rr * ptr_;
                    top0 = make_float2(tt * ptr_ - rr * bot0.y, tt * pti_ + rr * bot0.x);
                    bot0 = make_float2(nbx, nby);
                }
                {
                    const float ptr_ = c * top1.x - s * top1.y;
                    const float pti_ = c * top1.y + s * top1.x;
                    const float nbx = tt * bot1.x - rr * pti_;
                    const float nby = tt * bot1.y + rr * ptr_;
                    top1 = make_float2(tt * ptr_ - rr * bot1.y, tt * pti_ + rr * bot1.x);
                    bot1 = make_float2(nbx, nby);
                }
            }
            P[0][p].z = top0.x; P[0][p].w = top0.y;
            P[0][p + 1].x = bot0.x; P[0][p + 1].y = bot0.y;
            P[1][p].z = top1.x; P[1][p].w = top1.y;
            P[1][p + 1].x = bot1.x; P[1][p + 1].y = bot1.y;
        }
        __syncthreads();
    }

    const float4 v0 = P[0][p];
    const float4 v1 = P[1][p];
    float s0, c0, s1, c1;
    __sincosf(clamp02pi(pout[2 * p]),     &s0, &c0);
    __sincosf(clamp02pi(pout[2 * p + 1]), &s1, &c1);

    float4 w0, w1;
    w0.x = c0 * v0.x - s0 * v0.y;  w0.y = c0 * v0.y + s0 * v0.x;
    w0.z = c0 * v1.x - s0 * v1.y;  w0.w = c0 * v1.y + s0 * v1.x;
    w1.x = c1 * v0.z - s1 * v0.w;  w1.y = c1 * v0.w + s1 * v0.z;
    w1.z = c1 * v1.z - s1 * v1.w;  w1.w = c1 * v1.w + s1 * v1.z;

    const int i0 = (2 * p) * 512 + 2 * b;
    const int i1 = (2 * p + 1) * 512 + 2 * b;
    if (i0 + 1 < out_size) *(float2*)(out + i0) = make_float2(w0.x, w0.z);
    if (i1 + 1 < out_size) *(float2*)(out + i1) = make_float2(w1.x, w1.z);
}

extern "C" void kernel_launch(void* const* d_in, const int* in_sizes, int n_in,
                              void* d_out, int out_size, void* d_ws, size_t ws_size,
                              hipStream_t stream)
{
    const float* pe   = (const float*)d_in[0];  // pc_even_phases  [512][256]
    const float* po   = (const float*)d_in[1];  // pc_odd_phases   [512][255]
    const float* pout = (const float*)d_in[2];  // pc_out_phases   [512]
    const float* le   = (const float*)d_in[3];  // mmi_loss_even   [512][256]
    const float* ie   = (const float*)d_in[4];  // mmi_imb_even    [512][256]
    const float* lo   = (const float*)d_in[5];  // mmi_loss_odd    [512][255]
    const float* io   = (const float*)d_in[6];  // mmi_imb_odd     [512][255]

    const size_t need = (size_t)256 * 1024 * sizeof(float4);  // 4 MB
    if (ws_size >= need) {
        float4* Mc = (float4*)d_ws;
        compose_kernel<<<256, 512, 0, stream>>>(pe, po, le, ie, lo, io, Mc);
        mesh_pair_kernel<<<512, 256, 0, stream>>>(Mc, pout, (float*)d_out, out_size);
    } else {
        mesh_kernel<<<256, 256, 0, stream>>>(pe, po, pout, le, ie, lo, io,
                                             (float*)d_out, out_size);
    }
}